// Round 8
// baseline (380.969 us; speedup 1.0000x reference)
//
#include <hip/hip_runtime.h>
#include <stdint.h>

#define T_LEN 512
#define VOCAB 101
#define GSP   140   // bf16 G row pitch in shorts (280 B; keeps b64 8B-aligned)
#define XPB   516   // token row pitch bytes (512 + 2 replicated tail + pad)

typedef short short8 __attribute__((ext_vector_type(8)));
typedef float f32x4  __attribute__((ext_vector_type(4)));

#define LOG2E 1.442695041f
#define L2E2  2.885390082f   // 2*log2(e)

__device__ __forceinline__ float asF(uint32_t u) {
    union { uint32_t i; float f; } x; x.i = u; return x.f;
}
__device__ __forceinline__ float bf2f(uint16_t u) { return asF(((uint32_t)u) << 16); }
__device__ __forceinline__ float bf_lo(uint32_t u) { return asF(u << 16); }
__device__ __forceinline__ float bf_hi(uint32_t u) { return asF(u & 0xFFFF0000u); }
__device__ __forceinline__ uint16_t f2bf(float f) {
    union { float f; uint32_t i; } x; x.f = f;
    return (uint16_t)((x.i + 0x7FFFu + ((x.i >> 16) & 1u)) >> 16);
}
__device__ __forceinline__ float getw(const void* p, int i, bool isbf) {
    return isbf ? bf2f(((const uint16_t*)p)[i]) : ((const float*)p)[i];
}
__device__ __forceinline__ bool detect_bf16(const void* embp) {
    const uint16_t* u = (const uint16_t*)embp;
    int sane = 0;
    for (int i = 0; i < 64; ++i) {
        uint16_t v = u[i];
        int e = (v >> 7) & 0xFF;
        sane += ((e >= 100 && e <= 140) || ((v & 0x7FFFu) == 0)) ? 1 : 0;
    }
    return sane >= 56;
}

// gates, scalar form: preacts (i,f,g,o); i/f/o log2e-scaled, g 2log2e-scaled,
// CST = cell state (2log2e scale). 5 exp2 + 2 rcp. Same algebra as r1-r7 (verified).
#define GATES4(PI, PF, PG, PO, CST, HOUT)                                       \
  {                                                                             \
    float ai = __builtin_amdgcn_exp2f(-(PI));                                   \
    float af = __builtin_amdgcn_exp2f(-(PF));                                   \
    float ag = __builtin_amdgcn_exp2f(-(PG));                                   \
    float ao = __builtin_amdgcn_exp2f(-(PO));                                   \
    float uu = 1.f + ai, ww = 1.f + ag, zz = 1.f + af;                          \
    float uw = uu * ww;                                                         \
    float num = __builtin_fmaf(__builtin_fmaf(ww, -L2E2, 2.f * L2E2), zz,       \
                               (CST) * uw);                                     \
    float cs = num * __builtin_amdgcn_rcpf(zz * uw);                            \
    (CST) = cs;                                                                 \
    float ac = __builtin_amdgcn_exp2f(-cs);                                     \
    float t1 = 1.f + ac;                                                        \
    (HOUT) = (2.f - t1) * __builtin_amdgcn_rcpf((1.f + ao) * t1);               \
  }

__global__ __launch_bounds__(256, 2) void lstm_fused(
    const int* __restrict__ x, const void* __restrict__ emb,
    const void* __restrict__ Wx, const void* __restrict__ Wh,
    const void* __restrict__ bias, const void* __restrict__ Wfc,
    const void* __restrict__ bfc, void* __restrict__ out)
{
    __shared__ __align__(16) uint16_t Gl2[VOCAB * GSP];   // 28,280 B bf16 preact bias
    __shared__ __align__(16) uint8_t  xt8[8 * XPB];       //  4,128 B packed tokens

    const int tid = threadIdx.x;
    const int wl  = tid & 63;
    const int lw  = tid >> 6;        // wave 0..3: owns rows 2lw, 2lw+1 (block-local)
    const int n   = wl & 15;
    const int q   = wl >> 4;
    const int b0  = blockIdx.x * 8;  // 8 rows per block
    const int u   = n + 16 * (q >> 1);   // lane's gated unit
    const int rowG = 2 * lw + (q & 1);   // lane's gated row (block-local)

    const bool isbf = detect_bf16(emb);

    // ---- build G[v][u][g] = bf16( scale(g) * (emb[v]@Wx + b)[32g+u] ) ----
    for (int idx = tid; idx < VOCAB * 128; idx += 256) {
        int v = idx >> 7, cc = idx & 127;
        int uu = cc >> 2, g = cc & 3;
        int col = 32 * g + uu;
        float acc = getw(bias, col, isbf);
        #pragma unroll 8
        for (int k = 0; k < 32; ++k)
            acc += getw(emb, v * 32 + k, isbf) * getw(Wx, k * 128 + col, isbf);
        Gl2[v * GSP + cc] = f2bf(acc * ((g == 2) ? L2E2 : LOG2E));
    }
    // ---- pack x tokens to u8 (8 rows); replicate first 2 at [512..513] ----
    for (int i = tid; i < 1024; i += 256) {
        int row = i >> 7, c4 = i & 127;
        int4 vv = *(const int4*)&x[(b0 + row) * T_LEN + (c4 << 2)];
        uint32_t p = (uint32_t)(vv.x & 255) | ((uint32_t)(vv.y & 255) << 8) |
                     ((uint32_t)(vv.z & 255) << 16) | ((uint32_t)(vv.w & 255) << 24);
        ((uint32_t*)&xt8[row * XPB])[c4] = p;
    }
    if (tid < 16) {
        int row = tid >> 1, j = tid & 1;
        xt8[row * XPB + 512 + j] = (uint8_t)x[(b0 + row) * T_LEN + j];
    }

    // ---- Wh fragments, operand B of 8 tiles. Tile jt covers gatecols
    //      [16jt,16jt+16); B[k=8q+jj][col=n] = sc(jt>>1)*Wh[8q+jj][16jt+n].
    //      D[m][n] of tile jt = preact(row m&1, gatecol 16jt+n)  (A = h, rows
    //      replicated along m). Lane (n,q) reg r: m=4q+r -> row r&1, col n. ----
    short8 bfr[8];
    #pragma unroll
    for (int jt = 0; jt < 8; ++jt) {
        const float sc = ((jt >> 1) == 2) ? L2E2 : LOG2E;
        union { short8 v; uint16_t s[8]; } ub;
        #pragma unroll
        for (int jj = 0; jj < 8; ++jj)
            ub.s[jj] = f2bf(getw(Wh, (8 * q + jj) * 128 + 16 * jt + n, isbf) * sc);
        bfr[jt] = ub.v;
    }
    __syncthreads();   // the ONLY barrier. Nothing in the time loop syncs.

    const uint8_t* xr = &xt8[rowG * XPB];

    // bpermute addresses (constant per lane): A-fragment dword j2 = h dword
    // (row n&1, unitpair p=4q+j2); source lane = 32*(p>>3)+16*(n&1)+2*(p&7).
    #define MKADR(J2) (4 * (32 * ((4 * q + (J2)) >> 3) + 16 * (n & 1) + \
                            2 * ((4 * q + (J2)) & 7)))
    const int adr0 = MKADR(0), adr1 = MKADR(1), adr2 = MKADR(2), adr3 = MKADR(3);
    const bool selR = (q & 1) != 0;        // row -> accumulator reg
    const bool selH = ((q >> 1) & 1) != 0; // unit-half -> tile 2g / 2g+1
    const bool par  = (n & 1) != 0;        // unit parity for h packing

    float c0 = 0.f, hlast = 0.f;
    int aw0 = 0, aw1 = 0, aw2 = 0, aw3 = 0;   // A-fragment (h) dwords; h(-1)=0
    uint64_t grC = *(const uint64_t*)&Gl2[(int)xr[0] * GSP + 4 * u];
    int tokA = xr[1];
    const f32x4 Z = {0.f, 0.f, 0.f, 0.f};

    for (int t = 0; t < T_LEN; ++t) {
        union { int d[4]; short8 v; } ua;
        ua.d[0] = aw0; ua.d[1] = aw1; ua.d[2] = aw2; ua.d[3] = aw3;
        short8 af = ua.v;
        f32x4 s0 = __builtin_amdgcn_mfma_f32_16x16x32_bf16(af, bfr[0], Z, 0, 0, 0);
        f32x4 s1 = __builtin_amdgcn_mfma_f32_16x16x32_bf16(af, bfr[1], Z, 0, 0, 0);
        f32x4 s2 = __builtin_amdgcn_mfma_f32_16x16x32_bf16(af, bfr[2], Z, 0, 0, 0);
        f32x4 s3 = __builtin_amdgcn_mfma_f32_16x16x32_bf16(af, bfr[3], Z, 0, 0, 0);
        f32x4 s4 = __builtin_amdgcn_mfma_f32_16x16x32_bf16(af, bfr[4], Z, 0, 0, 0);
        f32x4 s5 = __builtin_amdgcn_mfma_f32_16x16x32_bf16(af, bfr[5], Z, 0, 0, 0);
        f32x4 s6 = __builtin_amdgcn_mfma_f32_16x16x32_bf16(af, bfr[6], Z, 0, 0, 0);
        f32x4 s7 = __builtin_amdgcn_mfma_f32_16x16x32_bf16(af, bfr[7], Z, 0, 0, 0);
        // prefetch G(t+1) and token(t+2) -- independent of this step's chain
        uint64_t grN = *(const uint64_t*)&Gl2[tokA * GSP + 4 * u];
        tokA = xr[t + 2];
        // mux: gate g preact = D reg (q&1) of tile 2g + (q>>1), col n
        float a0 = selR ? s0[1] : s0[0], b0v = selR ? s1[1] : s1[0];
        float pi = selH ? b0v : a0;
        float a1 = selR ? s2[1] : s2[0], b1v = selR ? s3[1] : s3[0];
        float pf = selH ? b1v : a1;
        float a2 = selR ? s4[1] : s4[0], b2v = selR ? s5[1] : s5[0];
        float pg = selH ? b2v : a2;
        float a3 = selR ? s6[1] : s6[0], b3v = selR ? s7[1] : s7[0];
        float po = selH ? b3v : a3;
        // add G (this step's, prefetched last step)
        uint32_t glo = (uint32_t)grC, ghi = (uint32_t)(grC >> 32);
        pi += bf_lo(glo); pf += bf_hi(glo);
        pg += bf_lo(ghi); po += bf_hi(ghi);
        float h0;
        GATES4(pi, pf, pg, po, c0, h0);
        hlast = h0;
        // pack unit-pair (partner = lane^1) and regather next A-fragment
        float ho  = __shfl_xor(h0, 1);
        float plo = par ? ho : h0;
        float phi = par ? h0 : ho;
        uint32_t hd;
        asm("v_cvt_pk_bf16_f32 %0, %1, %2" : "=v"(hd) : "v"(plo), "v"(phi));
        aw0 = __builtin_amdgcn_ds_bpermute(adr0, (int)hd);
        aw1 = __builtin_amdgcn_ds_bpermute(adr1, (int)hd);
        aw2 = __builtin_amdgcn_ds_bpermute(adr2, (int)hd);
        aw3 = __builtin_amdgcn_ds_bpermute(adr3, (int)hd);
        grC = grN;
    }

    // ---- epilogue: out = h(T-1) @ W_fc + b_fc. Lane holds h(row q&1, unit u).
    //      Reduce over lane bits {0..3,5} (bit4 = row stays). ----
    float p0 = hlast * getw(Wfc, u * 2 + 0, isbf);
    float p1 = hlast * getw(Wfc, u * 2 + 1, isbf);
    p0 += __shfl_xor(p0, 1);  p1 += __shfl_xor(p1, 1);
    p0 += __shfl_xor(p0, 2);  p1 += __shfl_xor(p1, 2);
    p0 += __shfl_xor(p0, 4);  p1 += __shfl_xor(p1, 4);
    p0 += __shfl_xor(p0, 8);  p1 += __shfl_xor(p1, 8);
    p0 += __shfl_xor(p0, 32); p1 += __shfl_xor(p1, 32);
    if (wl == 0 || wl == 16) {
        int grow = b0 + rowG;
        float o0 = p0 + getw(bfc, 0, isbf);
        float o1 = p1 + getw(bfc, 1, isbf);
        if (isbf) {
            ((uint16_t*)out)[grow * 2 + 0] = f2bf(o0);
            ((uint16_t*)out)[grow * 2 + 1] = f2bf(o1);
        } else {
            ((float*)out)[grow * 2 + 0] = o0;
            ((float*)out)[grow * 2 + 1] = o1;
        }
    }
}

extern "C" void kernel_launch(void* const* d_in, const int* in_sizes, int n_in,
                              void* d_out, int out_size, void* d_ws, size_t ws_size,
                              hipStream_t stream) {
    (void)in_sizes; (void)n_in; (void)d_ws; (void)ws_size; (void)out_size;
    const int* x = (const int*)d_in[0];
    lstm_fused<<<dim3(512), dim3(256), 0, stream>>>(
        x, d_in[1], d_in[2], d_in[3], d_in[4], d_in[5], d_in[6], d_out);
}

// Round 10
// 326.435 us; speedup vs baseline: 1.1671x; 1.1671x over previous
//
#include <hip/hip_runtime.h>
#include <stdint.h>

#define T_LEN 512
#define VOCAB 101
#define GSP   140   // bf16 G row pitch in shorts; layout [wv][q][jt][gate] (128 data + pad)
#define XPB   516   // token row pitch bytes (512 + 2 replicated tail + pad)
#define HPW   20    // h row pitch in dwords (16 data + 4 pad)
#define HB1   (16 * HPW)

typedef short short8 __attribute__((ext_vector_type(8)));
typedef float f32x4  __attribute__((ext_vector_type(4)));

#define LOG2E 1.442695041f
#define L2E2  2.885390082f   // 2*log2(e)
#define SB()  __builtin_amdgcn_sched_barrier(0)

__device__ __forceinline__ float asF(uint32_t u) {
    union { uint32_t i; float f; } x; x.i = u; return x.f;
}
__device__ __forceinline__ float bf2f(uint16_t u) { return asF(((uint32_t)u) << 16); }
__device__ __forceinline__ float bf_lo(uint32_t u) { return asF(u << 16); }
__device__ __forceinline__ float bf_hi(uint32_t u) { return asF(u & 0xFFFF0000u); }
__device__ __forceinline__ uint16_t f2bf(float f) {
    union { float f; uint32_t i; } x; x.f = f;
    return (uint16_t)((x.i + 0x7FFFu + ((x.i >> 16) & 1u)) >> 16);
}
__device__ __forceinline__ float getw(const void* p, int i, bool isbf) {
    return isbf ? bf2f(((const uint16_t*)p)[i]) : ((const float*)p)[i];
}
__device__ __forceinline__ bool detect_bf16(const void* embp) {
    const uint16_t* u = (const uint16_t*)embp;
    int sane = 0;
    for (int i = 0; i < 64; ++i) {
        uint16_t v = u[i];
        int e = (v >> 7) & 0xFF;
        sane += ((e >= 100 && e <= 140) || ((v & 0x7FFFu) == 0)) ? 1 : 0;
    }
    return sane >= 56;
}

// gates for one unit: preacts (i,f,g,o); i/f/o log2e-scaled, g 2log2e-scaled,
// CST = cell state (2log2e scale). 5 exp2 + 2 rcp. Same algebra as r1-r8 (verified).
#define GATES4(PI, PF, PG, PO, CST, HOUT)                                       \
  {                                                                             \
    float ai = __builtin_amdgcn_exp2f(-(PI));                                   \
    float af = __builtin_amdgcn_exp2f(-(PF));                                   \
    float ag = __builtin_amdgcn_exp2f(-(PG));                                   \
    float ao = __builtin_amdgcn_exp2f(-(PO));                                   \
    float uu = 1.f + ai, ww = 1.f + ag, zz = 1.f + af;                          \
    float uw = uu * ww;                                                         \
    float num = __builtin_fmaf(__builtin_fmaf(ww, -L2E2, 2.f * L2E2), zz,       \
                               (CST) * uw);                                     \
    float cs = num * __builtin_amdgcn_rcpf(zz * uw);                            \
    (CST) = cs;                                                                 \
    float ac = __builtin_amdgcn_exp2f(-cs);                                     \
    float t1 = 1.f + ac;                                                        \
    (HOUT) = (2.f - t1) * __builtin_amdgcn_rcpf((1.f + ao) * t1);               \
  }

// One timestep. Issue order pinned bfrag < G(t+1) < tok(t+2); lgkmcnt(2) waits
// exactly the bfrag (in-order DS retirement). G is the MFMA C-operand (unpacked
// from last step's b128, already retired). h is written to rows `row` AND
// `row+8`, so B-cols 8-15 replicate rows 0-7 and s1 at lanes n>=8 is directly
// the lane's preact -- selection is 4 register cndmasks, no cross-lane ops.
#define STEP_T(HRoff, HWoff, TOFF)                                                  \
  {                                                                                 \
    const uint32_t* hr = &hbuf[HRoff];                                              \
    uint16_t*       hw = (uint16_t*)&hbuf[HWoff];                                   \
    short8 bfrag = *(const short8*)&hr[n * HPW + 4 * q];                            \
    SB();                                                                           \
    short8 grN = *(const short8*)&Gl2[tokA * GSP + gofs];                           \
    SB();                                                                           \
    int tokN = xr[TOFF];                                                            \
    SB();                                                                           \
    f32x4 gc0, gc1;                                                                 \
    { union { short8 v; uint32_t d[4]; } ug; ug.v = grC;                            \
      gc0[0] = bf_lo(ug.d[0]); gc0[1] = bf_hi(ug.d[0]);                             \
      gc0[2] = bf_lo(ug.d[1]); gc0[3] = bf_hi(ug.d[1]);                             \
      gc1[0] = bf_lo(ug.d[2]); gc1[1] = bf_hi(ug.d[2]);                             \
      gc1[2] = bf_lo(ug.d[3]); gc1[3] = bf_hi(ug.d[3]); }                           \
    SB();                                                                           \
    asm volatile("s_waitcnt lgkmcnt(2)" ::: "memory");                              \
    SB();                                                                           \
    f32x4 s0 = __builtin_amdgcn_mfma_f32_16x16x32_bf16(afr0, bfrag, gc0, 0, 0, 0);  \
    f32x4 s1 = __builtin_amdgcn_mfma_f32_16x16x32_bf16(afr1, bfrag, gc1, 0, 0, 0);  \
    float pi = hiN ? s1[0] : s0[0];                                                 \
    float pf = hiN ? s1[1] : s0[1];                                                 \
    float pg = hiN ? s1[2] : s0[2];                                                 \
    float po = hiN ? s1[3] : s0[3];                                                 \
    float h0;                                                                       \
    GATES4(pi, pf, pg, po, c0, h0);                                                 \
    uint32_t hp;                                                                    \
    asm("v_cvt_pk_bf16_f32 %0, %1, %2" : "=v"(hp) : "v"(h0), "v"(h0));              \
    hw[row * (2 * HPW) + uG]       = (uint16_t)hp;                                  \
    hw[(row + 8) * (2 * HPW) + uG] = (uint16_t)hp;                                  \
    grC = grN; tokA = tokN;                                                         \
    SB();                                                                           \
    asm volatile("s_waitcnt lgkmcnt(0)" ::: "memory");                              \
    __builtin_amdgcn_s_barrier();                                                   \
    SB();                                                                           \
  }

__global__ __launch_bounds__(256, 2) void lstm_fused(
    const int* __restrict__ x, const void* __restrict__ emb,
    const void* __restrict__ Wx, const void* __restrict__ Wh,
    const void* __restrict__ bias, const void* __restrict__ Wfc,
    const void* __restrict__ bfc, void* __restrict__ out)
{
    __shared__ __align__(16) uint16_t Gl2[VOCAB * GSP];   // 28,280 B bf16 preact bias
    __shared__ __align__(16) uint8_t  xt8[8 * XPB];       //  4,128 B packed tokens
    __shared__ __align__(16) uint32_t hbuf[2 * 16 * HPW]; //  2,560 B dbl-buffered h

    const int tid = threadIdx.x;
    const int wl  = tid & 63;
    const int wv  = tid >> 6;       // wave 0..3: owns units 8wv..8wv+7
    const int n   = wl & 15;
    const int q   = wl >> 4;
    const int b0  = blockIdx.x * 8; // 8 rows per block
    const bool hiN = ((n >> 3) & 1) != 0;   // lane gates tile 1 (units +4..7)
    const int row = n & 7;          // lane's gated batch row
    const int uG  = 8 * wv + q + (hiN ? 4 : 0);   // lane's gated unit
    const int gofs = wv * 32 + q * 8;             // short-offset of lane's G b128

    const bool isbf = detect_bf16(emb);

    // ---- build G: store scale(g)*(emb[v]@Wx+b)[32g+u] at permuted
    //      [v][wv=u>>3][q=u&3][jt=(u>>2)&1][g] so lane's 2 C-frags = one b128 ----
    for (int idx = tid; idx < VOCAB * 128; idx += 256) {
        int v = idx >> 7, cc = idx & 127;
        int u = cc >> 2, g = cc & 3;
        int col = 32 * g + u;
        float acc = getw(bias, col, isbf);
        #pragma unroll 8
        for (int k = 0; k < 32; ++k)
            acc += getw(emb, v * 32 + k, isbf) * getw(Wx, k * 128 + col, isbf);
        int st = (u >> 3) * 32 + (u & 3) * 8 + ((u >> 2) & 1) * 4 + g;
        Gl2[v * GSP + st] = f2bf(acc * ((g == 2) ? L2E2 : LOG2E));
    }
    // ---- pack x tokens to u8 (8 rows); replicate first 2 at [512..513] ----
    for (int i = tid; i < 1024; i += 256) {
        int r = i >> 7, c4 = i & 127;
        int4 vv = *(const int4*)&x[(b0 + r) * T_LEN + (c4 << 2)];
        uint32_t p = (uint32_t)(vv.x & 255) | ((uint32_t)(vv.y & 255) << 8) |
                     ((uint32_t)(vv.z & 255) << 16) | ((uint32_t)(vv.w & 255) << 24);
        ((uint32_t*)&xt8[r * XPB])[c4] = p;
    }
    if (tid < 16) {
        int r = tid >> 1, j = tid & 1;
        xt8[r * XPB + 512 + j] = (uint8_t)x[(b0 + r) * T_LEN + j];
    }
    // ---- zero h buffers (rows 8..15 are maintained copies of 0..7) ----
    for (int i = tid; i < 2 * 16 * HPW; i += 256) hbuf[i] = 0;

    // ---- A fragments, tiles jt=0,1: D-row m of tile jt <-> (gate m&3,
    //      unit 8wv + 4jt + (m>>2)); A[m=n][k=8q+jj] = sc(n&3)*Wh[8q+jj][col],
    //      col = 32*(n&3) + 8wv + 4jt + (n>>2) ----
    short8 afr0, afr1;
    {
        const int gte = n & 3, ul = n >> 2;
        const float sc = (gte == 2) ? L2E2 : LOG2E;
        const int base = 32 * gte + 8 * wv + ul;
        union { short8 v; uint16_t s[8]; } u0, u1;
        #pragma unroll
        for (int jj = 0; jj < 8; ++jj) {
            int kk = 8 * q + jj;
            u0.s[jj] = f2bf(getw(Wh, kk * 128 + base,     isbf) * sc);
            u1.s[jj] = f2bf(getw(Wh, kk * 128 + base + 4, isbf) * sc);
        }
        afr0 = u0.v; afr1 = u1.v;
    }
    __syncthreads();
    // seed phase drift between co-resident blocks (~half-step offset)
    if (blockIdx.x & 1) __builtin_amdgcn_s_sleep(8);

    const uint8_t* xr = &xt8[row * XPB];
    float c0 = 0.f;
    short8 grC;
    int tokA;
    {
        int t0 = xr[0];
        tokA = xr[1];
        grC  = *(const short8*)&Gl2[t0 * GSP + gofs];
    }

    for (int t = 0; t < T_LEN; t += 2) {
        STEP_T(0,   HB1, t + 2);   // even: read buf0, write buf1
        STEP_T(HB1, 0,   t + 3);   // odd : read buf1, write buf0
    }

    __syncthreads();   // drain before epilogue

    // ---- epilogue: out = h(T-1) @ W_fc + b_fc ; h(511) lives in buf 0 ----
    if (tid < 16) {
        int r = tid >> 1, cc = tid & 1;
        float acc = getw(bfc, cc, isbf);
        #pragma unroll 8
        for (int k = 0; k < 32; ++k) {
            uint32_t d = hbuf[r * HPW + (k >> 1)];
            float hval = (k & 1) ? bf_hi(d) : bf_lo(d);
            acc += hval * getw(Wfc, k * 2 + cc, isbf);
        }
        int oidx = (b0 + r) * 2 + cc;
        if (isbf) ((uint16_t*)out)[oidx] = f2bf(acc);
        else      ((float*)out)[oidx]    = acc;
    }
}

extern "C" void kernel_launch(void* const* d_in, const int* in_sizes, int n_in,
                              void* d_out, int out_size, void* d_ws, size_t ws_size,
                              hipStream_t stream) {
    (void)in_sizes; (void)n_in; (void)d_ws; (void)ws_size; (void)out_size;
    const int* x = (const int*)d_in[0];
    lstm_fused<<<dim3(512), dim3(256), 0, stream>>>(
        x, d_in[1], d_in[2], d_in[3], d_in[4], d_in[5], d_in[6], d_out);
}

// Round 11
// 243.912 us; speedup vs baseline: 1.5619x; 1.3383x over previous
//
#include <hip/hip_runtime.h>
#include <stdint.h>

#define T_LEN 512
#define VOCAB 101
#define GSP   140   // bf16 G row pitch in shorts (280 B; 70 dw, gcd(70,32)=2)
#define XPB   516   // token row pitch bytes (512 + 4 replicated tail; dword-aligned rows)
#define HPW   20    // h row pitch in dwords (16 data + 4 pad; 2-way max alias on b128 = free)
#define HB1   (16 * HPW)

typedef short short8 __attribute__((ext_vector_type(8)));
typedef float f32x4  __attribute__((ext_vector_type(4)));

#define LOG2E 1.442695041f
#define L2E2  2.885390082f   // 2*log2(e)
#define SB()  __builtin_amdgcn_sched_barrier(0)

__device__ __forceinline__ float asF(uint32_t u) {
    union { uint32_t i; float f; } x; x.i = u; return x.f;
}
__device__ __forceinline__ float bf2f(uint16_t u) { return asF(((uint32_t)u) << 16); }
__device__ __forceinline__ float bf_lo(uint32_t u) { return asF(u << 16); }
__device__ __forceinline__ float bf_hi(uint32_t u) { return asF(u & 0xFFFF0000u); }
__device__ __forceinline__ uint16_t f2bf(float f) {
    union { float f; uint32_t i; } x; x.f = f;
    return (uint16_t)((x.i + 0x7FFFu + ((x.i >> 16) & 1u)) >> 16);
}
__device__ __forceinline__ float getw(const void* p, int i, bool isbf) {
    return isbf ? bf2f(((const uint16_t*)p)[i]) : ((const float*)p)[i];
}
__device__ __forceinline__ bool detect_bf16(const void* embp) {
    const uint16_t* u = (const uint16_t*)embp;
    int sane = 0;
    for (int i = 0; i < 64; ++i) {
        uint16_t v = u[i];
        int e = (v >> 7) & 0xFF;
        sane += ((e >= 100 && e <= 140) || ((v & 0x7FFFu) == 0)) ? 1 : 0;
    }
    return sane >= 56;
}

// gates for one unit: S = f32x4 preacts (i,f,g,o; i/f/o log2e-scaled, g 2log2e-scaled),
// CST = cell state (2log2e scale). 5 exp2 + 2 rcp. Verified r1-r10.
#define GATES(S, CST, HOUT)                                                     \
  {                                                                             \
    float ai = __builtin_amdgcn_exp2f(-(S)[0]);                                 \
    float af = __builtin_amdgcn_exp2f(-(S)[1]);                                 \
    float ag = __builtin_amdgcn_exp2f(-(S)[2]);                                 \
    float ao = __builtin_amdgcn_exp2f(-(S)[3]);                                 \
    float uu = 1.f + ai, ww = 1.f + ag, zz = 1.f + af;                          \
    float uw = uu * ww;                                                         \
    float num = __builtin_fmaf(__builtin_fmaf(ww, -L2E2, 2.f * L2E2), zz,       \
                               (CST) * uw);                                     \
    float cs = num * __builtin_amdgcn_rcpf(zz * uw);                            \
    (CST) = cs;                                                                 \
    float ac = __builtin_amdgcn_exp2f(-cs);                                     \
    float t1 = 1.f + ac;                                                        \
    (HOUT) = (2.f - t1) * __builtin_amdgcn_rcpf((1.f + ao) * t1);               \
  }

// One timestep (r6 structure). Issue order pinned: bfrag < G(t+1) < [tok32].
// In-order DS retirement => the counted wait retires exactly bfrag.
// GCUR was read >=1 step ago and force-retired by last step's lgkmcnt(0) drain,
// so its unpack runs under bfrag latency. TOKE is a register byte-extract
// (compile-time shift) -- no per-step token LDS op except the PH2 b32 refill.
#define STEP_T(HRoff, HWoff, GCUR, GNXT, TOKE, DOTOK, WAITA)                        \
  {                                                                                 \
    const uint32_t* hr = &hbuf[HRoff];                                              \
    uint16_t*       hw = (uint16_t*)&hbuf[HWoff];                                   \
    short8 bfrag = *(const short8*)&hr[n * HPW + 4 * q];                            \
    SB();                                                                           \
    GNXT = *(const uint64_t*)&Gl2[(int)(TOKE) * GSP + (u4 << 2)];                   \
    SB();                                                                           \
    DOTOK;                                                                          \
    SB();                                                                           \
    f32x4 gc;                                                                       \
    { uint32_t d0 = (uint32_t)(GCUR), d1 = (uint32_t)((GCUR) >> 32);                \
      gc[0] = bf_lo(d0); gc[1] = bf_hi(d0);                                         \
      gc[2] = bf_lo(d1); gc[3] = bf_hi(d1); }                                       \
    SB();                                                                           \
    asm volatile(WAITA ::: "memory");                                               \
    SB();                                                                           \
    f32x4 s0 = __builtin_amdgcn_mfma_f32_16x16x32_bf16(afr, bfrag, gc, 0, 0, 0);    \
    float h0;                                                                       \
    GATES(s0, c0, h0);                                                              \
    uint32_t hp;                                                                    \
    asm("v_cvt_pk_bf16_f32 %0, %1, %2" : "=v"(hp) : "v"(h0), "v"(h0));              \
    hw[n * (2 * HPW) + u4] = (uint16_t)hp;                                          \
    SB();                                                                           \
    asm volatile("s_waitcnt lgkmcnt(0)" ::: "memory");                              \
    __builtin_amdgcn_s_barrier();                                                   \
    SB();                                                                           \
  }

__global__ __launch_bounds__(512, 1) void lstm_fused(
    const int* __restrict__ x, const void* __restrict__ emb,
    const void* __restrict__ Wx, const void* __restrict__ Wh,
    const void* __restrict__ bias, const void* __restrict__ Wfc,
    const void* __restrict__ bfc, void* __restrict__ out)
{
    __shared__ __align__(16) uint16_t Gl2[VOCAB * GSP];     // 28,280 B bf16 preact bias
    __shared__ __align__(16) uint8_t  xt8[16 * XPB];        //  8,256 B packed tokens
    __shared__ __align__(16) uint32_t hbuf[2 * 16 * HPW];   //  2,560 B dbl-buffered h

    const int tid = threadIdx.x;
    const int wl  = tid & 63;
    const int w   = tid >> 6;       // wave 0..7: owns units 4w..4w+3
    const int n   = wl & 15;        // batch row within group
    const int q   = wl >> 4;        // lane owns unit 4w+q for row n
    const int u4  = 4 * w + q;      // the lane's unit
    const int b0  = blockIdx.x * 16;

    const bool isbf = detect_bf16(emb);

    // ---- build G[v][u][g] = bf16( scale(g) * (emb[v]@Wx + b)[32g+u] ) ----
    for (int idx = tid; idx < VOCAB * 128; idx += 512) {
        int v = idx >> 7, cc = idx & 127;
        int u = cc >> 2, g = cc & 3;
        int col = 32 * g + u;
        float acc = getw(bias, col, isbf);
        #pragma unroll 8
        for (int k = 0; k < 32; ++k)
            acc += getw(emb, v * 32 + k, isbf) * getw(Wx, k * 128 + col, isbf);
        Gl2[v * GSP + cc] = f2bf(acc * ((g == 2) ? L2E2 : LOG2E));
    }
    // ---- pack x tokens to u8; replicate first 4 at [512..515] (b32 tail) ----
    for (int i = tid; i < 2048; i += 512) {
        int row = i >> 7, c4 = i & 127;
        int4 vv = *(const int4*)&x[(b0 + row) * T_LEN + (c4 << 2)];
        uint32_t p = (uint32_t)(vv.x & 255) | ((uint32_t)(vv.y & 255) << 8) |
                     ((uint32_t)(vv.z & 255) << 16) | ((uint32_t)(vv.w & 255) << 24);
        ((uint32_t*)&xt8[row * XPB])[c4] = p;
    }
    if (tid < 64) {
        int row = tid >> 2, j = tid & 3;
        xt8[row * XPB + 512 + j] = (uint8_t)x[(b0 + row) * T_LEN + j];
    }
    // ---- zero h buffers ----
    for (int i = tid; i < 2 * 16 * HPW; i += 512) hbuf[i] = 0;

    // ---- A fragment: single 16x16 tile per wave. D-row m <-> (gate m&3,
    //      unit 4w + (m>>2)); A[m=n][k=8q+jj] = sc(n&3)*Wh[8q+jj][32*(n&3)+4w+(n>>2)].
    //      Lane (n,q) reg j = gate j of unit 4w+q, row n (r2/r6-verified mapping). ----
    short8 afr;
    {
        const int gte = n & 3, ul = n >> 2;
        const float sc = (gte == 2) ? L2E2 : LOG2E;
        const int base = 32 * gte + 4 * w + ul;
        union { short8 v; uint16_t s[8]; } u0;
        #pragma unroll
        for (int jj = 0; jj < 8; ++jj)
            u0.s[jj] = f2bf(getw(Wh, (8 * q + jj) * 128 + base, isbf) * sc);
        afr = u0.v;
    }
    __syncthreads();

    float c0 = 0.f;
    const uint8_t*  xr  = &xt8[n * XPB];
    const uint32_t* xrw = (const uint32_t*)xr;   // dword-aligned (XPB = 4*129)

    // ---- prologue: tw = tokens[0..3]; grA = G(token 0) ----
    uint32_t tw = xrw[0], twN = 0;
    uint64_t grA, grB;
    grA = *(const uint64_t*)&Gl2[(int)(tw & 255) * GSP + (u4 << 2)];

    for (int k = 0; k < T_LEN / 4; ++k) {
        // t = 4k+p; even p reads buf0/writes buf1. tok word refilled at p=2
        // (one step before use; p2's pre-barrier drain force-retires twN).
        STEP_T(0,   HB1, grA, grB, (tw >> 8) & 255,  (void)0,
               "s_waitcnt lgkmcnt(1)");
        STEP_T(HB1, 0,   grB, grA, (tw >> 16) & 255, (void)0,
               "s_waitcnt lgkmcnt(1)");
        STEP_T(0,   HB1, grA, grB, tw >> 24,         twN = xrw[k + 1],
               "s_waitcnt lgkmcnt(2)");
        STEP_T(HB1, 0,   grB, grA, twN & 255,        (void)0,
               "s_waitcnt lgkmcnt(1)");
        tw = twN;
    }

    __syncthreads();   // full drain before epilogue reads

    // ---- epilogue: out = h(T-1) @ W_fc + b_fc ; h(511) lives in buf 0 ----
    if (tid < 32) {
        int row = tid >> 1, cc = tid & 1;
        float acc = getw(bfc, cc, isbf);
        #pragma unroll 8
        for (int kk = 0; kk < 32; ++kk) {
            uint32_t d = hbuf[row * HPW + (kk >> 1)];
            float hval = (kk & 1) ? bf_hi(d) : bf_lo(d);
            acc += hval * getw(Wfc, kk * 2 + cc, isbf);
        }
        int oidx = (b0 + row) * 2 + cc;
        if (isbf) ((uint16_t*)out)[oidx] = f2bf(acc);
        else      ((float*)out)[oidx]    = acc;
    }
}

extern "C" void kernel_launch(void* const* d_in, const int* in_sizes, int n_in,
                              void* d_out, int out_size, void* d_ws, size_t ws_size,
                              hipStream_t stream) {
    (void)in_sizes; (void)n_in; (void)d_ws; (void)ws_size; (void)out_size;
    const int* x = (const int*)d_in[0];
    lstm_fused<<<dim3(256), dim3(512), 0, stream>>>(
        x, d_in[1], d_in[2], d_in[3], d_in[4], d_in[5], d_in[6], d_out);
}

// Round 12
// 242.765 us; speedup vs baseline: 1.5693x; 1.0047x over previous
//
#include <hip/hip_runtime.h>
#include <stdint.h>

#define T_LEN 512
#define VOCAB 101
#define GSP   140   // bf16 G row pitch in shorts (280 B; 70 dw, gcd(70,32)=2)
#define XPB   516   // token row pitch bytes (512 + 4 replicated tail; dword-aligned rows)
#define HPW   20    // h row pitch in dwords (16 data + 4 pad; 2-way max alias on b128 = free)
#define HB1   (16 * HPW)

typedef short short8 __attribute__((ext_vector_type(8)));
typedef float f32x4  __attribute__((ext_vector_type(4)));

#define LOG2E 1.442695041f
#define L2E2  2.885390082f   // 2*log2(e)
#define SB()  __builtin_amdgcn_sched_barrier(0)

__device__ __forceinline__ float asF(uint32_t u) {
    union { uint32_t i; float f; } x; x.i = u; return x.f;
}
__device__ __forceinline__ float bf2f(uint16_t u) { return asF(((uint32_t)u) << 16); }
__device__ __forceinline__ float bf_lo(uint32_t u) { return asF(u << 16); }
__device__ __forceinline__ float bf_hi(uint32_t u) { return asF(u & 0xFFFF0000u); }
__device__ __forceinline__ uint16_t f2bf(float f) {
    union { float f; uint32_t i; } x; x.f = f;
    return (uint16_t)((x.i + 0x7FFFu + ((x.i >> 16) & 1u)) >> 16);
}
__device__ __forceinline__ float getw(const void* p, int i, bool isbf) {
    return isbf ? bf2f(((const uint16_t*)p)[i]) : ((const float*)p)[i];
}
__device__ __forceinline__ bool detect_bf16(const void* embp) {
    const uint16_t* u = (const uint16_t*)embp;
    int sane = 0;
    for (int i = 0; i < 64; ++i) {
        uint16_t v = u[i];
        int e = (v >> 7) & 0xFF;
        sane += ((e >= 100 && e <= 140) || ((v & 0x7FFFu) == 0)) ? 1 : 0;
    }
    return sane >= 56;
}

// gates for one unit: S = f32x4 preacts (i,f,g,o; i/f/o log2e-scaled, g 2log2e-scaled),
// CST = cell state (2log2e scale). 5 exp2 + 2 rcp. Verified r1-r11.
#define GATES(S, CST, HOUT)                                                     \
  {                                                                             \
    float ai = __builtin_amdgcn_exp2f(-(S)[0]);                                 \
    float af = __builtin_amdgcn_exp2f(-(S)[1]);                                 \
    float ag = __builtin_amdgcn_exp2f(-(S)[2]);                                 \
    float ao = __builtin_amdgcn_exp2f(-(S)[3]);                                 \
    float uu = 1.f + ai, ww = 1.f + ag, zz = 1.f + af;                          \
    float uw = uu * ww;                                                         \
    float num = __builtin_fmaf(__builtin_fmaf(ww, -L2E2, 2.f * L2E2), zz,       \
                               (CST) * uw);                                     \
    float cs = num * __builtin_amdgcn_rcpf(zz * uw);                            \
    (CST) = cs;                                                                 \
    float ac = __builtin_amdgcn_exp2f(-cs);                                     \
    float t1 = 1.f + ac;                                                        \
    (HOUT) = (2.f - t1) * __builtin_amdgcn_rcpf((1.f + ao) * t1);               \
  }

// One timestep. KEY CHANGE vs r11: G(t+1)/tok reads are issued PRE-barrier
// (during the gates/write tail, LDS pipe idle) and stay in flight ACROSS the
// barrier (read-only region -> hazard-free). Post-barrier LDS burst = bfrags
// only. Pre-barrier counted wait (lgkmcnt(1)/(2)) retires exactly the h-write
// (issue order write < G < tok, in-order DS retirement). The mid-step
// lgkmcnt(0) formally retires G/tok too, but they are ~800 cyc old = free;
// it really waits only the bfrag. GCUR unpack sits under bfrag latency
// (compiler auto-inserts the counted wait for GCUR's long-retired read).
#define STEP_T(HRoff, HWoff, GCUR, GNXT, TOKE, DOTOK, WAITPRE)                      \
  {                                                                                 \
    const uint32_t* hr = &hbuf[HRoff];                                              \
    uint16_t*       hw = (uint16_t*)&hbuf[HWoff];                                   \
    short8 bfrag = *(const short8*)&hr[n * HPW + 4 * q];                            \
    SB();                                                                           \
    f32x4 gc;                                                                       \
    { uint32_t d0 = (uint32_t)(GCUR), d1 = (uint32_t)((GCUR) >> 32);                \
      gc[0] = bf_lo(d0); gc[1] = bf_hi(d0);                                         \
      gc[2] = bf_lo(d1); gc[3] = bf_hi(d1); }                                       \
    SB();                                                                           \
    asm volatile("s_waitcnt lgkmcnt(0)" ::: "memory");                              \
    SB();                                                                           \
    f32x4 s0 = __builtin_amdgcn_mfma_f32_16x16x32_bf16(afr, bfrag, gc, 0, 0, 0);    \
    float h0;                                                                       \
    GATES(s0, c0, h0);                                                              \
    uint32_t hp;                                                                    \
    asm("v_cvt_pk_bf16_f32 %0, %1, %2" : "=v"(hp) : "v"(h0), "v"(h0));              \
    hw[n * (2 * HPW) + u4] = (uint16_t)hp;                                          \
    SB();                                                                           \
    GNXT = *(const uint64_t*)&Gl2[(int)(TOKE) * GSP + (u4 << 2)];                   \
    SB();                                                                           \
    DOTOK;                                                                          \
    SB();                                                                           \
    asm volatile(WAITPRE ::: "memory");                                             \
    __builtin_amdgcn_s_barrier();                                                   \
    SB();                                                                           \
  }

__global__ __launch_bounds__(512, 1) void lstm_fused(
    const int* __restrict__ x, const void* __restrict__ emb,
    const void* __restrict__ Wx, const void* __restrict__ Wh,
    const void* __restrict__ bias, const void* __restrict__ Wfc,
    const void* __restrict__ bfc, void* __restrict__ out)
{
    __shared__ __align__(16) uint16_t Gl2[VOCAB * GSP];     // 28,280 B bf16 preact bias
    __shared__ __align__(16) uint8_t  xt8[16 * XPB];        //  8,256 B packed tokens
    __shared__ __align__(16) uint32_t hbuf[2 * 16 * HPW];   //  2,560 B dbl-buffered h

    const int tid = threadIdx.x;
    const int wl  = tid & 63;
    const int w   = tid >> 6;       // wave 0..7: owns units 4w..4w+3
    const int n   = wl & 15;        // batch row within group
    const int q   = wl >> 4;        // lane owns unit 4w+q for row n
    const int u4  = 4 * w + q;      // the lane's unit
    const int b0  = blockIdx.x * 16;

    const bool isbf = detect_bf16(emb);

    // ---- build G[v][u][g] = bf16( scale(g) * (emb[v]@Wx + b)[32g+u] ) ----
    for (int idx = tid; idx < VOCAB * 128; idx += 512) {
        int v = idx >> 7, cc = idx & 127;
        int u = cc >> 2, g = cc & 3;
        int col = 32 * g + u;
        float acc = getw(bias, col, isbf);
        #pragma unroll 8
        for (int k = 0; k < 32; ++k)
            acc += getw(emb, v * 32 + k, isbf) * getw(Wx, k * 128 + col, isbf);
        Gl2[v * GSP + cc] = f2bf(acc * ((g == 2) ? L2E2 : LOG2E));
    }
    // ---- pack x tokens to u8; replicate first 4 at [512..515] (b32 tail) ----
    for (int i = tid; i < 2048; i += 512) {
        int row = i >> 7, c4 = i & 127;
        int4 vv = *(const int4*)&x[(b0 + row) * T_LEN + (c4 << 2)];
        uint32_t p = (uint32_t)(vv.x & 255) | ((uint32_t)(vv.y & 255) << 8) |
                     ((uint32_t)(vv.z & 255) << 16) | ((uint32_t)(vv.w & 255) << 24);
        ((uint32_t*)&xt8[row * XPB])[c4] = p;
    }
    if (tid < 64) {
        int row = tid >> 2, j = tid & 3;
        xt8[row * XPB + 512 + j] = (uint8_t)x[(b0 + row) * T_LEN + j];
    }
    // ---- zero h buffers ----
    for (int i = tid; i < 2 * 16 * HPW; i += 512) hbuf[i] = 0;

    // ---- A fragment: single 16x16 tile per wave. D-row m <-> (gate m&3,
    //      unit 4w + (m>>2)); A[m=n][k=8q+jj] = sc(n&3)*Wh[8q+jj][32*(n&3)+4w+(n>>2)].
    //      Lane (n,q) reg j = gate j of unit 4w+q, row n (r2/r6-verified mapping). ----
    short8 afr;
    {
        const int gte = n & 3, ul = n >> 2;
        const float sc = (gte == 2) ? L2E2 : LOG2E;
        const int base = 32 * gte + 4 * w + ul;
        union { short8 v; uint16_t s[8]; } u0;
        #pragma unroll
        for (int jj = 0; jj < 8; ++jj)
            u0.s[jj] = f2bf(getw(Wh, (8 * q + jj) * 128 + base, isbf) * sc);
        afr = u0.v;
    }
    __syncthreads();

    float c0 = 0.f;
    const uint8_t*  xr  = &xt8[n * XPB];
    const uint32_t* xrw = (const uint32_t*)xr;   // dword-aligned (XPB = 4*129)

    // ---- prologue: tw = tokens[0..3]; grA = G(token 0) ----
    uint32_t tw = xrw[0], twN = 0;
    uint64_t grA, grB;
    grA = *(const uint64_t*)&Gl2[(int)(tw & 255) * GSP + (u4 << 2)];

    for (int k = 0; k < T_LEN / 4; ++k) {
        // t = 4k+p; even p reads buf0/writes buf1. tok word refilled at p=2
        // (value used at p=3's pre-barrier G-issue, one full step later).
        STEP_T(0,   HB1, grA, grB, (tw >> 8) & 255,  (void)0,
               "s_waitcnt lgkmcnt(1)");
        STEP_T(HB1, 0,   grB, grA, (tw >> 16) & 255, (void)0,
               "s_waitcnt lgkmcnt(1)");
        STEP_T(0,   HB1, grA, grB, tw >> 24,         twN = xrw[k + 1],
               "s_waitcnt lgkmcnt(2)");
        STEP_T(HB1, 0,   grB, grA, twN & 255,        (void)0,
               "s_waitcnt lgkmcnt(1)");
        tw = twN;
    }

    __syncthreads();   // full drain before epilogue reads

    // ---- epilogue: out = h(T-1) @ W_fc + b_fc ; h(511) lives in buf 0 ----
    if (tid < 32) {
        int row = tid >> 1, cc = tid & 1;
        float acc = getw(bfc, cc, isbf);
        #pragma unroll 8
        for (int kk = 0; kk < 32; ++kk) {
            uint32_t d = hbuf[row * HPW + (kk >> 1)];
            float hval = (kk & 1) ? bf_hi(d) : bf_lo(d);
            acc += hval * getw(Wfc, kk * 2 + cc, isbf);
        }
        int oidx = (b0 + row) * 2 + cc;
        if (isbf) ((uint16_t*)out)[oidx] = f2bf(acc);
        else      ((float*)out)[oidx]    = acc;
    }
}

extern "C" void kernel_launch(void* const* d_in, const int* in_sizes, int n_in,
                              void* d_out, int out_size, void* d_ws, size_t ws_size,
                              hipStream_t stream) {
    (void)in_sizes; (void)n_in; (void)d_ws; (void)ws_size; (void)out_size;
    const int* x = (const int*)d_in[0];
    lstm_fused<<<dim3(256), dim3(512), 0, stream>>>(
        x, d_in[1], d_in[2], d_in[3], d_in[4], d_in[5], d_in[6], d_out);
}